// Round 2
// baseline (27533.539 us; speedup 1.0000x reference)
//
#include <hip/hip_runtime.h>
#include <math.h>

#define FEAT 1024
#define NB 16       // batch
#define NT 256      // seq len
#define VOCAB 32000
#define G3 3072     // 3*FEAT
#define NWG 256     // scan workgroups (== CUs, 1 block/CU via 62KB LDS)

// ---------------- embedding gather: xs[t*NB+b][:] = emb[x[b][t]] ----------------
__global__ __launch_bounds__(256) void gather_kernel(const int* __restrict__ x,
                                                     const float* __restrict__ emb,
                                                     float* __restrict__ xs) {
    int row = blockIdx.x;          // row = t*NB + b  (time-major)
    int t = row >> 4;
    int b = row & 15;
    int tok = x[b * NT + t];
    const float4* src = (const float4*)(emb + (size_t)tok * FEAT);
    float4* dst = (float4*)(xs + (size_t)row * FEAT);
    dst[threadIdx.x] = src[threadIdx.x];   // 256 threads * 4 floats = 1024
}

// ---------------- generic fp32 tiled GEMM:  C[M][N] = A[M][K] * B[N][K]^T + bias[N] ----
// perm!=0: A row m is fetched from row ((m&255)<<4)|(m>>8)   (b*T+t -> t*B+b map)
__global__ __launch_bounds__(256) void gemm_f32(const float* __restrict__ A,
                                                const float* __restrict__ Bm,
                                                const float* __restrict__ bias,
                                                float* __restrict__ C,
                                                int M, int N, int K, int perm) {
    __shared__ float As[8][132];
    __shared__ float Bs[8][132];

    int n0 = blockIdx.x * 128;
    int m0 = blockIdx.y * 128;
    int tid = threadIdx.x;
    int tx = tid & 15, ty = tid >> 4;
    int lrow = tid >> 1;
    int lk = (tid & 1) * 4;

    int am = m0 + lrow;
    if (perm) am = ((am & 255) << 4) | (am >> 8);
    const float* aptr = A + (size_t)am * K + lk;
    const float* bptr = Bm + (size_t)(n0 + lrow) * K + lk;

    float acc[8][8];
#pragma unroll
    for (int i = 0; i < 8; i++)
#pragma unroll
        for (int j = 0; j < 8; j++) acc[i][j] = 0.f;

    for (int k0 = 0; k0 < K; k0 += 8) {
        float4 av = *(const float4*)(aptr + k0);
        float4 bv = *(const float4*)(bptr + k0);
        __syncthreads();
        As[lk + 0][lrow] = av.x; As[lk + 1][lrow] = av.y;
        As[lk + 2][lrow] = av.z; As[lk + 3][lrow] = av.w;
        Bs[lk + 0][lrow] = bv.x; Bs[lk + 1][lrow] = bv.y;
        Bs[lk + 2][lrow] = bv.z; Bs[lk + 3][lrow] = bv.w;
        __syncthreads();
#pragma unroll
        for (int kk = 0; kk < 8; kk++) {
            float4 a0 = *(const float4*)&As[kk][ty * 8];
            float4 a1 = *(const float4*)&As[kk][ty * 8 + 4];
            float4 b0 = *(const float4*)&Bs[kk][tx * 8];
            float4 b1 = *(const float4*)&Bs[kk][tx * 8 + 4];
            float a[8] = {a0.x, a0.y, a0.z, a0.w, a1.x, a1.y, a1.z, a1.w};
            float b[8] = {b0.x, b0.y, b0.z, b0.w, b1.x, b1.y, b1.z, b1.w};
#pragma unroll
            for (int i = 0; i < 8; i++)
#pragma unroll
                for (int j = 0; j < 8; j++)
                    acc[i][j] = fmaf(a[i], b[j], acc[i][j]);
        }
    }

#pragma unroll
    for (int i = 0; i < 8; i++) {
        int m = m0 + ty * 8 + i;
        float* crow = C + (size_t)m * N + n0 + tx * 8;
#pragma unroll
        for (int j = 0; j < 8; j++)
            crow[j] = acc[i][j] + bias[n0 + tx * 8 + j];
    }
}

// ---------------- hand-rolled grid barrier (device-scope, XCD-safe) ----------------
// bar[0] = arrive counter, bar[1] = generation. Generation-based: read gen,
// arrive, last block resets counter then bumps gen (release); others spin with
// acquire loads. __threadfence() emits the L2 wb/inv needed across XCDs.
__device__ __forceinline__ void grid_barrier(unsigned* bar, int tid) {
    __syncthreads();                    // drains this block's vmem (vmcnt 0)
    if (tid == 0) {
        unsigned g = __hip_atomic_load(&bar[1], __ATOMIC_RELAXED, __HIP_MEMORY_SCOPE_AGENT);
        __threadfence();                // release: write back our stores
        unsigned a = __hip_atomic_fetch_add(&bar[0], 1u, __ATOMIC_ACQ_REL, __HIP_MEMORY_SCOPE_AGENT);
        if (a == NWG - 1) {
            __hip_atomic_store(&bar[0], 0u, __ATOMIC_RELAXED, __HIP_MEMORY_SCOPE_AGENT);
            __hip_atomic_fetch_add(&bar[1], 1u, __ATOMIC_RELEASE, __HIP_MEMORY_SCOPE_AGENT);
        } else {
            int spins = 0;
            while (__hip_atomic_load(&bar[1], __ATOMIC_ACQUIRE, __HIP_MEMORY_SCOPE_AGENT) == g) {
                if (++spins > (1 << 17)) break;   // safety valve: wrong > hung
                __builtin_amdgcn_s_sleep(2);
            }
        }
        __threadfence();                // acquire: invalidate L1/L2 for whole block
    }
    __syncthreads();
}

// ---------------- persistent GRU scan (one layer), plain launch ----------------
// 256 WGs x 256 threads, 1 block/CU (62KB LDS). WG wg owns columns [wg*4, wg*4+4).
__global__ __launch_bounds__(256, 1) void gru_scan(const float* __restrict__ xp,
                                                   const float* __restrict__ Whh,
                                                   const float* __restrict__ bhh,
                                                   const float* __restrict__ h0src,
                                                   float* __restrict__ ys,
                                                   float* __restrict__ buf0,
                                                   float* __restrict__ buf1,
                                                   float* __restrict__ hid,
                                                   unsigned* bar) {
    __shared__ float w_lds[12 * 1028];      // stride 1028 to break bank alignment
    __shared__ float red[16 * 192];
    __shared__ float sum_lds[192];
    __shared__ float bhh_lds[12];

    int wg = blockIdx.x;
    int j0 = wg * 4;
    int tid = threadIdx.x;

    // stage the 12 W_hh rows for this WG into LDS (coalesced float4)
    for (int rr = 0; rr < 12; rr++) {
        int gate = rr >> 2, jloc = rr & 3;
        int grow = gate * FEAT + j0 + jloc;
        float4 v = ((const float4*)(Whh + (size_t)grow * FEAT))[tid];
        *(float4*)(w_lds + rr * 1028 + tid * 4) = v;
    }
    if (tid < 12) {
        int gate = tid >> 2, jloc = tid & 3;
        bhh_lds[tid] = bhh[gate * FEAT + j0 + jloc];
    }
    __syncthreads();

    int kc = tid >> 4;        // 0..15 : k-chunk (strided)
    int tile = tid & 15;
    int rg = tile >> 2;       // 0..3 : row-group (3 rows each)
    int bg = tile & 3;        // 0..3 : batch-group (4 b each)

    for (int t = 0; t < NT; t++) {
        const float* hc = (t == 0) ? h0src : ((t & 1) ? buf0 : buf1);
        float* hn = (t & 1) ? buf1 : buf0;

        float4 acc[4][3];
#pragma unroll
        for (int bi = 0; bi < 4; bi++)
#pragma unroll
            for (int c = 0; c < 3; c++) acc[bi][c] = make_float4(0.f, 0.f, 0.f, 0.f);

#pragma unroll
        for (int i = 0; i < 16; i++) {
            int k = i * 64 + kc * 4;     // strided k-chunks spread LDS banks
            float4 w4[3];
#pragma unroll
            for (int c = 0; c < 3; c++)
                w4[c] = *(const float4*)&w_lds[(rg * 3 + c) * 1028 + k];
#pragma unroll
            for (int bi = 0; bi < 4; bi++) {
                int b = bg * 4 + bi;
                float4 h4 = *(const float4*)&hc[b * FEAT + k];
#pragma unroll
                for (int c = 0; c < 3; c++) {
                    acc[bi][c].x = fmaf(h4.x, w4[c].x, acc[bi][c].x);
                    acc[bi][c].y = fmaf(h4.y, w4[c].y, acc[bi][c].y);
                    acc[bi][c].z = fmaf(h4.z, w4[c].z, acc[bi][c].z);
                    acc[bi][c].w = fmaf(h4.w, w4[c].w, acc[bi][c].w);
                }
            }
        }
#pragma unroll
        for (int bi = 0; bi < 4; bi++)
#pragma unroll
            for (int c = 0; c < 3; c++) {
                float s = acc[bi][c].x + acc[bi][c].y + acc[bi][c].z + acc[bi][c].w;
                int o = (rg * 3 + c) * 16 + bg * 4 + bi;
                red[kc * 192 + o] = s;
            }
        __syncthreads();
        if (tid < 192) {
            float s = 0.f;
#pragma unroll
            for (int q = 0; q < 16; q++) s += red[q * 192 + tid];
            sum_lds[tid] = s;
        }
        __syncthreads();
        if (tid < 64) {
            int b = tid >> 2, jl = tid & 3;
            int j = j0 + jl;
            const float* xpr = xp + (size_t)(t * NB + b) * G3;
            float dr = sum_lds[jl * 16 + b] + bhh_lds[jl];
            float dz = sum_lds[(4 + jl) * 16 + b] + bhh_lds[4 + jl];
            float dn = sum_lds[(8 + jl) * 16 + b] + bhh_lds[8 + jl];
            float r = 1.f / (1.f + expf(-(xpr[j] + dr)));
            float z = 1.f / (1.f + expf(-(xpr[FEAT + j] + dz)));
            float n = tanhf(xpr[2 * FEAT + j] + r * dn);
            float hold = hc[b * FEAT + j];
            float hv = (1.f - z) * n + z * hold;
            hn[b * FEAT + j] = hv;
            ys[(size_t)(t * NB + b) * FEAT + j] = hv;
            if (t == NT - 1) hid[b * FEAT + j] = hv;
        }
        grid_barrier(bar, tid);
    }
}

// ---------------- launcher ----------------
extern "C" void kernel_launch(void* const* d_in, const int* in_sizes, int n_in,
                              void* d_out, int out_size, void* d_ws, size_t ws_size,
                              hipStream_t stream) {
    const int*   x     = (const int*)d_in[0];
    const float* h0    = (const float*)d_in[1];
    const float* emb   = (const float*)d_in[2];
    const float* W_ih0 = (const float*)d_in[3];
    const float* W_hh0 = (const float*)d_in[4];
    const float* b_ih0 = (const float*)d_in[5];
    const float* b_hh0 = (const float*)d_in[6];
    const float* W_ih1 = (const float*)d_in[7];
    const float* W_hh1 = (const float*)d_in[8];
    const float* b_ih1 = (const float*)d_in[9];
    const float* b_hh1 = (const float*)d_in[10];
    const float* dec_b = (const float*)d_in[11];

    float* out = (float*)d_out;
    float* hid_out = out + (size_t)NB * NT * VOCAB;

    float* ws  = (float*)d_ws;
    float* xp  = ws;                                    // [4096][3072]
    float* xs  = xp + (size_t)4096 * 3072;              // [4096][1024] (also ys1)
    float* ys0 = xs + (size_t)4096 * 1024;              // [4096][1024]
    float* ha  = ys0 + (size_t)4096 * 1024;             // [16][1024]
    float* hb  = ha + NB * FEAT;                        // [16][1024]
    unsigned* bar = (unsigned*)(hb + NB * FEAT);        // 2 uints
    float* ys1 = xs;                                    // reuse (xs dead after xp0)

    // 0. zero the grid-barrier state (counter, generation)
    hipMemsetAsync((void*)bar, 0, 2 * sizeof(unsigned), stream);

    // 1. gather
    gather_kernel<<<dim3(NT * NB), dim3(256), 0, stream>>>(x, emb, xs);

    // 2. x_proj layer 0
    gemm_f32<<<dim3(G3 / 128, 4096 / 128), dim3(256), 0, stream>>>(
        xs, W_ih0, b_ih0, xp, 4096, G3, FEAT, 0);

    // 3. scan layer 0 (persistent, hand-rolled grid barrier)
    gru_scan<<<dim3(NWG), dim3(256), 0, stream>>>(
        xp, W_hh0, b_hh0, h0, ys0, ha, hb, hid_out, bar);

    // 4. x_proj layer 1 (reuses xp)
    gemm_f32<<<dim3(G3 / 128, 4096 / 128), dim3(256), 0, stream>>>(
        ys0, W_ih1, b_ih1, xp, 4096, G3, FEAT, 0);

    // 5. scan layer 1 (barrier continues from prior generation; counter is 0)
    gru_scan<<<dim3(NWG), dim3(256), 0, stream>>>(
        xp, W_hh1, b_hh1, h0 + NB * FEAT, ys1, ha, hb, hid_out + NB * FEAT, bar);

    // 6. tied decoder: logits[b*T+t][v] = ys1[t*B+b] . emb[v] + dec_b[v]
    gemm_f32<<<dim3(VOCAB / 128, 4096 / 128), dim3(256), 0, stream>>>(
        ys1, emb, dec_b, out, 4096, VOCAB, FEAT, 1);
}

// Round 3
// 26588.049 us; speedup vs baseline: 1.0356x; 1.0356x over previous
//
#include <hip/hip_runtime.h>
#include <math.h>

#define FEAT 1024
#define NB 16       // batch
#define NT 256      // seq len
#define VOCAB 32000
#define G3 3072     // 3*FEAT
#define NWG 256     // scan workgroups
#define FLAG_STRIDE 32   // 128B between flags -> no cacheline sharing

// ---------------- embedding gather: xs[t*NB+b][:] = emb[x[b][t]] ----------------
__global__ __launch_bounds__(256) void gather_kernel(const int* __restrict__ x,
                                                     const float* __restrict__ emb,
                                                     float* __restrict__ xs) {
    int row = blockIdx.x;          // row = t*NB + b  (time-major)
    int t = row >> 4;
    int b = row & 15;
    int tok = x[b * NT + t];
    const float4* src = (const float4*)(emb + (size_t)tok * FEAT);
    float4* dst = (float4*)(xs + (size_t)row * FEAT);
    dst[threadIdx.x] = src[threadIdx.x];   // 256 threads * 4 floats = 1024
}

// ---------------- generic fp32 tiled GEMM:  C[M][N] = A[M][K] * B[N][K]^T + bias[N] ----
// perm!=0: A row m is fetched from row ((m&255)<<4)|(m>>8)   (b*T+t -> t*B+b map)
__global__ __launch_bounds__(256) void gemm_f32(const float* __restrict__ A,
                                                const float* __restrict__ Bm,
                                                const float* __restrict__ bias,
                                                float* __restrict__ C,
                                                int M, int N, int K, int perm) {
    __shared__ float As[8][132];
    __shared__ float Bs[8][132];

    int n0 = blockIdx.x * 128;
    int m0 = blockIdx.y * 128;
    int tid = threadIdx.x;
    int tx = tid & 15, ty = tid >> 4;
    int lrow = tid >> 1;
    int lk = (tid & 1) * 4;

    int am = m0 + lrow;
    if (perm) am = ((am & 255) << 4) | (am >> 8);
    const float* aptr = A + (size_t)am * K + lk;
    const float* bptr = Bm + (size_t)(n0 + lrow) * K + lk;

    float acc[8][8];
#pragma unroll
    for (int i = 0; i < 8; i++)
#pragma unroll
        for (int j = 0; j < 8; j++) acc[i][j] = 0.f;

    for (int k0 = 0; k0 < K; k0 += 8) {
        float4 av = *(const float4*)(aptr + k0);
        float4 bv = *(const float4*)(bptr + k0);
        __syncthreads();
        As[lk + 0][lrow] = av.x; As[lk + 1][lrow] = av.y;
        As[lk + 2][lrow] = av.z; As[lk + 3][lrow] = av.w;
        Bs[lk + 0][lrow] = bv.x; Bs[lk + 1][lrow] = bv.y;
        Bs[lk + 2][lrow] = bv.z; Bs[lk + 3][lrow] = bv.w;
        __syncthreads();
#pragma unroll
        for (int kk = 0; kk < 8; kk++) {
            float4 a0 = *(const float4*)&As[kk][ty * 8];
            float4 a1 = *(const float4*)&As[kk][ty * 8 + 4];
            float4 b0 = *(const float4*)&Bs[kk][tx * 8];
            float4 b1 = *(const float4*)&Bs[kk][tx * 8 + 4];
            float a[8] = {a0.x, a0.y, a0.z, a0.w, a1.x, a1.y, a1.z, a1.w};
            float b[8] = {b0.x, b0.y, b0.z, b0.w, b1.x, b1.y, b1.z, b1.w};
#pragma unroll
            for (int i = 0; i < 8; i++)
#pragma unroll
                for (int j = 0; j < 8; j++)
                    acc[i][j] = fmaf(a[i], b[j], acc[i][j]);
        }
    }

#pragma unroll
    for (int i = 0; i < 8; i++) {
        int m = m0 + ty * 8 + i;
        float* crow = C + (size_t)m * N + n0 + tx * 8;
#pragma unroll
        for (int j = 0; j < 8; j++)
            crow[j] = acc[i][j] + bias[n0 + tx * 8 + j];
    }
}

// ---------------- contention-free grid barrier ----------------
// Arrive: block bid release-stores `expected` to its private flag (128B apart).
// Detect: block 0's 256 threads poll the 256 flags in PARALLEL (acquire loads),
//         then tid0 release-stores the generation word.
// Release: other blocks spin on the generation word (read-only).
// No atomic RMW anywhere -> no cross-XCD serialization.
__device__ __forceinline__ void grid_barrier2(unsigned* __restrict__ flags,
                                              unsigned* __restrict__ gen,
                                              unsigned expected, int bid, int tid) {
    __syncthreads();                    // all lanes' global stores issued
    if (tid == 0) {
        __threadfence();                // release: write back h/ys stores
        __hip_atomic_store(&flags[bid * FLAG_STRIDE], expected,
                           __ATOMIC_RELEASE, __HIP_MEMORY_SCOPE_AGENT);
    }
    if (bid == 0) {
        unsigned v; int spins = 0;
        do {
            v = __hip_atomic_load(&flags[tid * FLAG_STRIDE],
                                  __ATOMIC_ACQUIRE, __HIP_MEMORY_SCOPE_AGENT);
        } while (v < expected && ++spins < (1 << 18));
        __syncthreads();                // all 256 flags seen
        if (tid == 0) {
            __threadfence();            // acquire: invalidate CU L1
            __hip_atomic_store(gen, expected,
                               __ATOMIC_RELEASE, __HIP_MEMORY_SCOPE_AGENT);
        }
    } else {
        if (tid == 0) {
            unsigned v; int spins = 0;
            do {
                v = __hip_atomic_load(gen, __ATOMIC_ACQUIRE,
                                      __HIP_MEMORY_SCOPE_AGENT);
                if (v >= expected) break;
                __builtin_amdgcn_s_sleep(1);
            } while (++spins < (1 << 18));
            __threadfence();            // acquire: invalidate CU L1
        }
    }
    __syncthreads();
}

// ---------------- persistent GRU scan (one layer) ----------------
// 256 WGs x 256 threads. WG wg owns output columns [wg*4, wg*4+4).
// W_hh slice (12 rows) LDS-resident; per step 16x12 matvec + gating.
__global__ __launch_bounds__(256, 1) void gru_scan(const float* __restrict__ xp,
                                                   const float* __restrict__ Whh,
                                                   const float* __restrict__ bhh,
                                                   const float* __restrict__ h0src,
                                                   float* __restrict__ ys,
                                                   float* __restrict__ buf0,
                                                   float* __restrict__ buf1,
                                                   float* __restrict__ hid,
                                                   unsigned* __restrict__ flags,
                                                   unsigned* __restrict__ gen,
                                                   unsigned gen_base) {
    __shared__ float w_lds[12 * 1028];      // stride 1028 to break bank alignment
    __shared__ float red[16 * 192];
    __shared__ float sum_lds[192];
    __shared__ float bhh_lds[12];

    int wg = blockIdx.x;
    int j0 = wg * 4;
    int tid = threadIdx.x;

    // stage the 12 W_hh rows for this WG into LDS (coalesced float4)
    for (int rr = 0; rr < 12; rr++) {
        int gate = rr >> 2, jloc = rr & 3;
        int grow = gate * FEAT + j0 + jloc;
        float4 v = ((const float4*)(Whh + (size_t)grow * FEAT))[tid];
        *(float4*)(w_lds + rr * 1028 + tid * 4) = v;
    }
    if (tid < 12) {
        int gate = tid >> 2, jloc = tid & 3;
        bhh_lds[tid] = bhh[gate * FEAT + j0 + jloc];
    }
    __syncthreads();

    int kc = tid >> 4;        // 0..15 : k-chunk (strided)
    int tile = tid & 15;
    int rg = tile >> 2;       // 0..3 : row-group (3 rows each)
    int bg = tile & 3;        // 0..3 : batch-group (4 b each)

    for (int t = 0; t < NT; t++) {
        const float* hc = (t == 0) ? h0src : ((t & 1) ? buf0 : buf1);
        float* hn = (t & 1) ? buf1 : buf0;

        // ---- prefetch xp gate values + h_old (overlaps the matvec below) ----
        float xr = 0.f, xz = 0.f, xn = 0.f, hold = 0.f;
        int pb = tid >> 2, pjl = tid & 3, pj = j0 + pjl;
        if (tid < 64) {
            const float* xpr = xp + (size_t)(t * NB + pb) * G3;
            xr = xpr[pj];
            xz = xpr[FEAT + pj];
            xn = xpr[2 * FEAT + pj];
            hold = hc[pb * FEAT + pj];
        }

        float4 acc[4][3];
#pragma unroll
        for (int bi = 0; bi < 4; bi++)
#pragma unroll
            for (int c = 0; c < 3; c++) acc[bi][c] = make_float4(0.f, 0.f, 0.f, 0.f);

#pragma unroll
        for (int i = 0; i < 16; i++) {
            int k = i * 64 + kc * 4;     // strided k-chunks spread LDS banks
            float4 w4[3];
#pragma unroll
            for (int c = 0; c < 3; c++)
                w4[c] = *(const float4*)&w_lds[(rg * 3 + c) * 1028 + k];
#pragma unroll
            for (int bi = 0; bi < 4; bi++) {
                int b = bg * 4 + bi;
                float4 h4 = *(const float4*)&hc[b * FEAT + k];
#pragma unroll
                for (int c = 0; c < 3; c++) {
                    acc[bi][c].x = fmaf(h4.x, w4[c].x, acc[bi][c].x);
                    acc[bi][c].y = fmaf(h4.y, w4[c].y, acc[bi][c].y);
                    acc[bi][c].z = fmaf(h4.z, w4[c].z, acc[bi][c].z);
                    acc[bi][c].w = fmaf(h4.w, w4[c].w, acc[bi][c].w);
                }
            }
        }
#pragma unroll
        for (int bi = 0; bi < 4; bi++)
#pragma unroll
            for (int c = 0; c < 3; c++) {
                float s = acc[bi][c].x + acc[bi][c].y + acc[bi][c].z + acc[bi][c].w;
                int o = (rg * 3 + c) * 16 + bg * 4 + bi;
                red[kc * 192 + o] = s;
            }
        __syncthreads();
        if (tid < 192) {
            float s = 0.f;
#pragma unroll
            for (int q = 0; q < 16; q++) s += red[q * 192 + tid];
            sum_lds[tid] = s;
        }
        __syncthreads();
        if (tid < 64) {
            float dr = sum_lds[pjl * 16 + pb] + bhh_lds[pjl];
            float dz = sum_lds[(4 + pjl) * 16 + pb] + bhh_lds[4 + pjl];
            float dn = sum_lds[(8 + pjl) * 16 + pb] + bhh_lds[8 + pjl];
            float r = 1.f / (1.f + expf(-(xr + dr)));
            float z = 1.f / (1.f + expf(-(xz + dz)));
            float n = tanhf(xn + r * dn);
            float hv = (1.f - z) * n + z * hold;
            hn[pb * FEAT + pj] = hv;
            ys[(size_t)(t * NB + pb) * FEAT + pj] = hv;
            if (t == NT - 1) hid[pb * FEAT + pj] = hv;
        }
        grid_barrier2(flags, gen, gen_base + t + 1, wg, tid);
    }
}

// ---------------- launcher ----------------
extern "C" void kernel_launch(void* const* d_in, const int* in_sizes, int n_in,
                              void* d_out, int out_size, void* d_ws, size_t ws_size,
                              hipStream_t stream) {
    const int*   x     = (const int*)d_in[0];
    const float* h0    = (const float*)d_in[1];
    const float* emb   = (const float*)d_in[2];
    const float* W_ih0 = (const float*)d_in[3];
    const float* W_hh0 = (const float*)d_in[4];
    const float* b_ih0 = (const float*)d_in[5];
    const float* b_hh0 = (const float*)d_in[6];
    const float* W_ih1 = (const float*)d_in[7];
    const float* W_hh1 = (const float*)d_in[8];
    const float* b_ih1 = (const float*)d_in[9];
    const float* b_hh1 = (const float*)d_in[10];
    const float* dec_b = (const float*)d_in[11];

    float* out = (float*)d_out;
    float* hid_out = out + (size_t)NB * NT * VOCAB;

    float* ws  = (float*)d_ws;
    float* xp  = ws;                                    // [4096][3072]
    float* xs  = xp + (size_t)4096 * 3072;              // [4096][1024] (also ys1)
    float* ys0 = xs + (size_t)4096 * 1024;              // [4096][1024]
    float* ha  = ys0 + (size_t)4096 * 1024;             // [16][1024]
    float* hb  = ha + NB * FEAT;                        // [16][1024]
    unsigned* flags = (unsigned*)(hb + NB * FEAT);      // 256 * 32 uints (128B apart)
    unsigned* gen   = flags + NWG * FLAG_STRIDE;        // 1 uint
    float* ys1 = xs;                                    // reuse (xs dead after xp0)

    // 0. zero the barrier state (flags + gen)
    hipMemsetAsync((void*)flags, 0, (NWG * FLAG_STRIDE + 1) * sizeof(unsigned), stream);

    // 1. gather
    gather_kernel<<<dim3(NT * NB), dim3(256), 0, stream>>>(x, emb, xs);

    // 2. x_proj layer 0
    gemm_f32<<<dim3(G3 / 128, 4096 / 128), dim3(256), 0, stream>>>(
        xs, W_ih0, b_ih0, xp, 4096, G3, FEAT, 0);

    // 3. scan layer 0 (persistent, flag-array grid barrier; gens 1..256)
    gru_scan<<<dim3(NWG), dim3(256), 0, stream>>>(
        xp, W_hh0, b_hh0, h0, ys0, ha, hb, hid_out, flags, gen, 0u);

    // 4. x_proj layer 1 (reuses xp)
    gemm_f32<<<dim3(G3 / 128, 4096 / 128), dim3(256), 0, stream>>>(
        ys0, W_ih1, b_ih1, xp, 4096, G3, FEAT, 0);

    // 5. scan layer 1 (gens 257..512)
    gru_scan<<<dim3(NWG), dim3(256), 0, stream>>>(
        xp, W_hh1, b_hh1, h0 + NB * FEAT, ys1, ha, hb, hid_out + NB * FEAT,
        flags, gen, (unsigned)NT);

    // 6. tied decoder: logits[b*T+t][v] = ys1[t*B+b] . emb[v] + dec_b[v]
    gemm_f32<<<dim3(VOCAB / 128, 4096 / 128), dim3(256), 0, stream>>>(
        ys1, emb, dec_b, out, 4096, VOCAB, FEAT, 1);
}

// Round 4
// 13054.486 us; speedup vs baseline: 2.1091x; 2.0367x over previous
//
#include <hip/hip_runtime.h>
#include <math.h>

#define FEAT 1024
#define NB 16       // batch
#define NT 256      // seq len
#define VOCAB 32000
#define G3 3072     // 3*FEAT
#define NWG 256     // scan workgroups
#define FLAG_STRIDE 32   // 128B between flags -> no cacheline sharing

// ---------------- embedding gather: xs[t*NB+b][:] = emb[x[b][t]] ----------------
__global__ __launch_bounds__(256) void gather_kernel(const int* __restrict__ x,
                                                     const float* __restrict__ emb,
                                                     float* __restrict__ xs) {
    int row = blockIdx.x;          // row = t*NB + b  (time-major)
    int t = row >> 4;
    int b = row & 15;
    int tok = x[b * NT + t];
    const float4* src = (const float4*)(emb + (size_t)tok * FEAT);
    float4* dst = (float4*)(xs + (size_t)row * FEAT);
    dst[threadIdx.x] = src[threadIdx.x];   // 256 threads * 4 floats = 1024
}

// ---------------- generic fp32 tiled GEMM:  C[M][N] = A[M][K] * B[N][K]^T + bias[N] ----
// perm!=0: A row m is fetched from row ((m&255)<<4)|(m>>8)   (b*T+t -> t*B+b map)
__global__ __launch_bounds__(256) void gemm_f32(const float* __restrict__ A,
                                                const float* __restrict__ Bm,
                                                const float* __restrict__ bias,
                                                float* __restrict__ C,
                                                int M, int N, int K, int perm) {
    __shared__ float As[8][132];
    __shared__ float Bs[8][132];

    int n0 = blockIdx.x * 128;
    int m0 = blockIdx.y * 128;
    int tid = threadIdx.x;
    int tx = tid & 15, ty = tid >> 4;
    int lrow = tid >> 1;
    int lk = (tid & 1) * 4;

    int am = m0 + lrow;
    if (perm) am = ((am & 255) << 4) | (am >> 8);
    const float* aptr = A + (size_t)am * K + lk;
    const float* bptr = Bm + (size_t)(n0 + lrow) * K + lk;

    float acc[8][8];
#pragma unroll
    for (int i = 0; i < 8; i++)
#pragma unroll
        for (int j = 0; j < 8; j++) acc[i][j] = 0.f;

    for (int k0 = 0; k0 < K; k0 += 8) {
        float4 av = *(const float4*)(aptr + k0);
        float4 bv = *(const float4*)(bptr + k0);
        __syncthreads();
        As[lk + 0][lrow] = av.x; As[lk + 1][lrow] = av.y;
        As[lk + 2][lrow] = av.z; As[lk + 3][lrow] = av.w;
        Bs[lk + 0][lrow] = bv.x; Bs[lk + 1][lrow] = bv.y;
        Bs[lk + 2][lrow] = bv.z; Bs[lk + 3][lrow] = bv.w;
        __syncthreads();
#pragma unroll
        for (int kk = 0; kk < 8; kk++) {
            float4 a0 = *(const float4*)&As[kk][ty * 8];
            float4 a1 = *(const float4*)&As[kk][ty * 8 + 4];
            float4 b0 = *(const float4*)&Bs[kk][tx * 8];
            float4 b1 = *(const float4*)&Bs[kk][tx * 8 + 4];
            float a[8] = {a0.x, a0.y, a0.z, a0.w, a1.x, a1.y, a1.z, a1.w};
            float b[8] = {b0.x, b0.y, b0.z, b0.w, b1.x, b1.y, b1.z, b1.w};
#pragma unroll
            for (int i = 0; i < 8; i++)
#pragma unroll
                for (int j = 0; j < 8; j++)
                    acc[i][j] = fmaf(a[i], b[j], acc[i][j]);
        }
    }

#pragma unroll
    for (int i = 0; i < 8; i++) {
        int m = m0 + ty * 8 + i;
        float* crow = C + (size_t)m * N + n0 + tx * 8;
#pragma unroll
        for (int j = 0; j < 8; j++)
            crow[j] = acc[i][j] + bias[n0 + tx * 8 + j];
    }
}

// ---------------- relaxed-poll grid barrier ----------------
// Key gfx950 fact: agent-scope ACQUIRE ops emit buffer_inv (invalidate whole
// XCD L2); RELEASE ops emit buffer_wbl2. Polling with acquire loads therefore
// nukes L2 every iteration (round-3 bug: 44us/step, 3-6x overfetch).
// Here: poll with RELAXED atomics (single-line LLC reads, no cache maint),
// and do exactly ONE release fence at arrive + ONE acquire fence at exit.
__device__ __forceinline__ void grid_barrier3(unsigned* __restrict__ flags,
                                              unsigned* __restrict__ gen,
                                              unsigned expected, int bid, int tid) {
    __syncthreads();                    // all lanes' h/ys stores issued
    if (tid == 0) {
        __builtin_amdgcn_fence(__ATOMIC_RELEASE, "agent");   // one wbl2
        __hip_atomic_store(&flags[bid * FLAG_STRIDE], expected,
                           __ATOMIC_RELAXED, __HIP_MEMORY_SCOPE_AGENT);
    }
    if (bid == 0) {
        // 256 threads poll the 256 flags in parallel, relaxed
        unsigned v; int spins = 0;
        do {
            v = __hip_atomic_load(&flags[tid * FLAG_STRIDE],
                                  __ATOMIC_RELAXED, __HIP_MEMORY_SCOPE_AGENT);
        } while (v < expected && ++spins < (1 << 18));
        __syncthreads();                // all 256 flags seen
        if (tid == 0) {
            __builtin_amdgcn_fence(__ATOMIC_ACQ_REL, "agent"); // inv for our h reads,
                                                               // order gen store after polls
            __hip_atomic_store(gen, expected,
                               __ATOMIC_RELAXED, __HIP_MEMORY_SCOPE_AGENT);
        }
    } else {
        if (tid == 0) {
            unsigned v; int spins = 0;
            do {
                v = __hip_atomic_load(gen, __ATOMIC_RELAXED,
                                      __HIP_MEMORY_SCOPE_AGENT);
                if (v >= expected) break;
                __builtin_amdgcn_s_sleep(1);
            } while (++spins < (1 << 18));
            __builtin_amdgcn_fence(__ATOMIC_ACQUIRE, "agent"); // one inv
        }
    }
    __syncthreads();
}

// ---------------- persistent GRU scan (one layer) ----------------
// 256 WGs x 256 threads. WG wg owns output columns [wg*4, wg*4+4).
// W_hh slice (12 rows) LDS-resident; per step 16x12 matvec + gating.
__global__ __launch_bounds__(256, 1) void gru_scan(const float* __restrict__ xp,
                                                   const float* __restrict__ Whh,
                                                   const float* __restrict__ bhh,
                                                   const float* __restrict__ h0src,
                                                   float* __restrict__ ys,
                                                   float* __restrict__ buf0,
                                                   float* __restrict__ buf1,
                                                   float* __restrict__ hid,
                                                   unsigned* __restrict__ flags,
                                                   unsigned* __restrict__ gen,
                                                   unsigned gen_base) {
    __shared__ float w_lds[12 * 1028];      // stride 1028 to break bank alignment
    __shared__ float red[16 * 192];
    __shared__ float sum_lds[192];
    __shared__ float bhh_lds[12];

    int wg = blockIdx.x;
    int j0 = wg * 4;
    int tid = threadIdx.x;

    // stage the 12 W_hh rows for this WG into LDS (coalesced float4)
    for (int rr = 0; rr < 12; rr++) {
        int gate = rr >> 2, jloc = rr & 3;
        int grow = gate * FEAT + j0 + jloc;
        float4 v = ((const float4*)(Whh + (size_t)grow * FEAT))[tid];
        *(float4*)(w_lds + rr * 1028 + tid * 4) = v;
    }
    if (tid < 12) {
        int gate = tid >> 2, jloc = tid & 3;
        bhh_lds[tid] = bhh[gate * FEAT + j0 + jloc];
    }
    __syncthreads();

    int kc = tid >> 4;        // 0..15 : k-chunk (strided)
    int tile = tid & 15;
    int rg = tile >> 2;       // 0..3 : row-group (3 rows each)
    int bg = tile & 3;        // 0..3 : batch-group (4 b each)

    for (int t = 0; t < NT; t++) {
        const float* hc = (t == 0) ? h0src : ((t & 1) ? buf0 : buf1);
        float* hn = (t & 1) ? buf1 : buf0;

        // ---- prefetch xp gate values + h_old (overlaps the matvec below) ----
        float xr = 0.f, xz = 0.f, xn = 0.f, hold = 0.f;
        int pb = tid >> 2, pjl = tid & 3, pj = j0 + pjl;
        if (tid < 64) {
            const float* xpr = xp + (size_t)(t * NB + pb) * G3;
            xr = xpr[pj];
            xz = xpr[FEAT + pj];
            xn = xpr[2 * FEAT + pj];
            hold = hc[pb * FEAT + pj];
        }

        float4 acc[4][3];
#pragma unroll
        for (int bi = 0; bi < 4; bi++)
#pragma unroll
            for (int c = 0; c < 3; c++) acc[bi][c] = make_float4(0.f, 0.f, 0.f, 0.f);

#pragma unroll
        for (int i = 0; i < 16; i++) {
            int k = i * 64 + kc * 4;     // strided k-chunks spread LDS banks
            float4 w4[3];
#pragma unroll
            for (int c = 0; c < 3; c++)
                w4[c] = *(const float4*)&w_lds[(rg * 3 + c) * 1028 + k];
#pragma unroll
            for (int bi = 0; bi < 4; bi++) {
                int b = bg * 4 + bi;
                float4 h4 = *(const float4*)&hc[b * FEAT + k];
#pragma unroll
                for (int c = 0; c < 3; c++) {
                    acc[bi][c].x = fmaf(h4.x, w4[c].x, acc[bi][c].x);
                    acc[bi][c].y = fmaf(h4.y, w4[c].y, acc[bi][c].y);
                    acc[bi][c].z = fmaf(h4.z, w4[c].z, acc[bi][c].z);
                    acc[bi][c].w = fmaf(h4.w, w4[c].w, acc[bi][c].w);
                }
            }
        }
#pragma unroll
        for (int bi = 0; bi < 4; bi++)
#pragma unroll
            for (int c = 0; c < 3; c++) {
                float s = acc[bi][c].x + acc[bi][c].y + acc[bi][c].z + acc[bi][c].w;
                int o = (rg * 3 + c) * 16 + bg * 4 + bi;
                red[kc * 192 + o] = s;
            }
        __syncthreads();
        if (tid < 192) {
            float s = 0.f;
#pragma unroll
            for (int q = 0; q < 16; q++) s += red[q * 192 + tid];
            sum_lds[tid] = s;
        }
        __syncthreads();
        if (tid < 64) {
            float dr = sum_lds[pjl * 16 + pb] + bhh_lds[pjl];
            float dz = sum_lds[(4 + pjl) * 16 + pb] + bhh_lds[4 + pjl];
            float dn = sum_lds[(8 + pjl) * 16 + pb] + bhh_lds[8 + pjl];
            float r = 1.f / (1.f + expf(-(xr + dr)));
            float z = 1.f / (1.f + expf(-(xz + dz)));
            float n = tanhf(xn + r * dn);
            float hv = (1.f - z) * n + z * hold;
            hn[pb * FEAT + pj] = hv;
            ys[(size_t)(t * NB + pb) * FEAT + pj] = hv;
            if (t == NT - 1) hid[pb * FEAT + pj] = hv;
        }
        grid_barrier3(flags, gen, gen_base + t + 1, wg, tid);
    }
}

// ---------------- launcher ----------------
extern "C" void kernel_launch(void* const* d_in, const int* in_sizes, int n_in,
                              void* d_out, int out_size, void* d_ws, size_t ws_size,
                              hipStream_t stream) {
    const int*   x     = (const int*)d_in[0];
    const float* h0    = (const float*)d_in[1];
    const float* emb   = (const float*)d_in[2];
    const float* W_ih0 = (const float*)d_in[3];
    const float* W_hh0 = (const float*)d_in[4];
    const float* b_ih0 = (const float*)d_in[5];
    const float* b_hh0 = (const float*)d_in[6];
    const float* W_ih1 = (const float*)d_in[7];
    const float* W_hh1 = (const float*)d_in[8];
    const float* b_ih1 = (const float*)d_in[9];
    const float* b_hh1 = (const float*)d_in[10];
    const float* dec_b = (const float*)d_in[11];

    float* out = (float*)d_out;
    float* hid_out = out + (size_t)NB * NT * VOCAB;

    float* ws  = (float*)d_ws;
    float* xp  = ws;                                    // [4096][3072]
    float* xs  = xp + (size_t)4096 * 3072;              // [4096][1024] (also ys1)
    float* ys0 = xs + (size_t)4096 * 1024;              // [4096][1024]
    float* ha  = ys0 + (size_t)4096 * 1024;             // [16][1024]
    float* hb  = ha + NB * FEAT;                        // [16][1024]
    unsigned* flags = (unsigned*)(hb + NB * FEAT);      // 256 * 32 uints (128B apart)
    unsigned* gen   = flags + NWG * FLAG_STRIDE;        // 1 uint
    float* ys1 = xs;                                    // reuse (xs dead after xp0)

    // 0. zero the barrier state (flags + gen)
    hipMemsetAsync((void*)flags, 0, (NWG * FLAG_STRIDE + 1) * sizeof(unsigned), stream);

    // 1. gather
    gather_kernel<<<dim3(NT * NB), dim3(256), 0, stream>>>(x, emb, xs);

    // 2. x_proj layer 0
    gemm_f32<<<dim3(G3 / 128, 4096 / 128), dim3(256), 0, stream>>>(
        xs, W_ih0, b_ih0, xp, 4096, G3, FEAT, 0);

    // 3. scan layer 0 (persistent, relaxed-poll grid barrier; gens 1..256)
    gru_scan<<<dim3(NWG), dim3(256), 0, stream>>>(
        xp, W_hh0, b_hh0, h0, ys0, ha, hb, hid_out, flags, gen, 0u);

    // 4. x_proj layer 1 (reuses xp)
    gemm_f32<<<dim3(G3 / 128, 4096 / 128), dim3(256), 0, stream>>>(
        ys0, W_ih1, b_ih1, xp, 4096, G3, FEAT, 0);

    // 5. scan layer 1 (gens 257..512)
    gru_scan<<<dim3(NWG), dim3(256), 0, stream>>>(
        xp, W_hh1, b_hh1, h0 + NB * FEAT, ys1, ha, hb, hid_out + NB * FEAT,
        flags, gen, (unsigned)NT);

    // 6. tied decoder: logits[b*T+t][v] = ys1[t*B+b] . emb[v] + dec_b[v]
    gemm_f32<<<dim3(VOCAB / 128, 4096 / 128), dim3(256), 0, stream>>>(
        ys1, emb, dec_b, out, 4096, VOCAB, FEAT, 1);
}

// Round 5
// 6611.332 us; speedup vs baseline: 4.1646x; 1.9746x over previous
//
#include <hip/hip_runtime.h>
#include <math.h>

#define FEAT 1024
#define NB 16       // batch
#define NT 256      // seq len
#define VOCAB 32000
#define G3 3072     // 3*FEAT
#define NWG 256     // scan workgroups
#define FLAG_STRIDE 32   // 128B between flags -> no cacheline sharing

typedef float f4 __attribute__((ext_vector_type(4)));

// ---------------- embedding gather: xs[t*NB+b][:] = emb[x[b][t]] ----------------
__global__ __launch_bounds__(256) void gather_kernel(const int* __restrict__ x,
                                                     const float* __restrict__ emb,
                                                     float* __restrict__ xs) {
    int row = blockIdx.x;          // row = t*NB + b  (time-major)
    int t = row >> 4;
    int b = row & 15;
    int tok = x[b * NT + t];
    const float4* src = (const float4*)(emb + (size_t)tok * FEAT);
    float4* dst = (float4*)(xs + (size_t)row * FEAT);
    dst[threadIdx.x] = src[threadIdx.x];   // 256 threads * 4 floats = 1024
}

// ---------------- generic fp32 tiled GEMM:  C[M][N] = A[M][K] * B[N][K]^T + bias[N] ----
// perm!=0: A row m is fetched from row ((m&255)<<4)|(m>>8)   (b*T+t -> t*B+b map)
__global__ __launch_bounds__(256) void gemm_f32(const float* __restrict__ A,
                                                const float* __restrict__ Bm,
                                                const float* __restrict__ bias,
                                                float* __restrict__ C,
                                                int M, int N, int K, int perm) {
    __shared__ float As[8][132];
    __shared__ float Bs[8][132];

    int n0 = blockIdx.x * 128;
    int m0 = blockIdx.y * 128;
    int tid = threadIdx.x;
    int tx = tid & 15, ty = tid >> 4;
    int lrow = tid >> 1;
    int lk = (tid & 1) * 4;

    int am = m0 + lrow;
    if (perm) am = ((am & 255) << 4) | (am >> 8);
    const float* aptr = A + (size_t)am * K + lk;
    const float* bptr = Bm + (size_t)(n0 + lrow) * K + lk;

    float acc[8][8];
#pragma unroll
    for (int i = 0; i < 8; i++)
#pragma unroll
        for (int j = 0; j < 8; j++) acc[i][j] = 0.f;

    for (int k0 = 0; k0 < K; k0 += 8) {
        float4 av = *(const float4*)(aptr + k0);
        float4 bv = *(const float4*)(bptr + k0);
        __syncthreads();
        As[lk + 0][lrow] = av.x; As[lk + 1][lrow] = av.y;
        As[lk + 2][lrow] = av.z; As[lk + 3][lrow] = av.w;
        Bs[lk + 0][lrow] = bv.x; Bs[lk + 1][lrow] = bv.y;
        Bs[lk + 2][lrow] = bv.z; Bs[lk + 3][lrow] = bv.w;
        __syncthreads();
#pragma unroll
        for (int kk = 0; kk < 8; kk++) {
            float4 a0 = *(const float4*)&As[kk][ty * 8];
            float4 a1 = *(const float4*)&As[kk][ty * 8 + 4];
            float4 b0 = *(const float4*)&Bs[kk][tx * 8];
            float4 b1 = *(const float4*)&Bs[kk][tx * 8 + 4];
            float a[8] = {a0.x, a0.y, a0.z, a0.w, a1.x, a1.y, a1.z, a1.w};
            float b[8] = {b0.x, b0.y, b0.z, b0.w, b1.x, b1.y, b1.z, b1.w};
#pragma unroll
            for (int i = 0; i < 8; i++)
#pragma unroll
                for (int j = 0; j < 8; j++)
                    acc[i][j] = fmaf(a[i], b[j], acc[i][j]);
        }
    }

#pragma unroll
    for (int i = 0; i < 8; i++) {
        int m = m0 + ty * 8 + i;
        float* crow = C + (size_t)m * N + n0 + tx * 8;
#pragma unroll
        for (int j = 0; j < 8; j++)
            crow[j] = acc[i][j] + bias[n0 + tx * 8 + j];
    }
}

// ---------------- agent-coherent scalar ops (bypass non-coherent L2, hit LLC) ----
__device__ __forceinline__ void store_f32_sc(float* p, float v) {
    asm volatile("global_store_dword %0, %1, off sc0 sc1" :: "v"(p), "v"(v) : "memory");
}

// ---------------- fence-free grid barrier ----------------
// All cross-block data (h, flags, gen) moves via sc0/sc1 ops -> always at LLC.
// No buffer_wbl2 / buffer_inv anywhere: L2 stays warm for xp/W across steps.
// Ordering: __syncthreads() drains vmcnt(0) per wave -> h stores at LLC before
// the flag store; readers use sc1 loads so they can't see stale L2.
__device__ __forceinline__ void grid_barrier4(unsigned* __restrict__ flags,
                                              unsigned* __restrict__ gen,
                                              unsigned expected, int bid, int tid) {
    __syncthreads();                    // drains all waves' sc1 h-stores
    if (tid == 0) {
        __hip_atomic_store(&flags[bid * FLAG_STRIDE], expected,
                           __ATOMIC_RELAXED, __HIP_MEMORY_SCOPE_AGENT);
    }
    if (bid == 0) {
        unsigned v; int spins = 0;
        do {
            v = __hip_atomic_load(&flags[tid * FLAG_STRIDE],
                                  __ATOMIC_RELAXED, __HIP_MEMORY_SCOPE_AGENT);
        } while (v < expected && ++spins < (1 << 18));
        __syncthreads();                // all 256 flags seen
        if (tid == 0) {
            __hip_atomic_store(gen, expected,
                               __ATOMIC_RELAXED, __HIP_MEMORY_SCOPE_AGENT);
        }
    } else {
        if (tid == 0) {
            unsigned v; int spins = 0;
            do {
                v = __hip_atomic_load(gen, __ATOMIC_RELAXED,
                                      __HIP_MEMORY_SCOPE_AGENT);
                if (v >= expected) break;
                __builtin_amdgcn_s_sleep(1);
            } while (++spins < (1 << 18));
        }
    }
    __syncthreads();
}

// ---------------- persistent GRU scan (one layer) ----------------
// 256 WGs x 256 threads. WG wg owns output columns [wg*4, wg*4+4).
// Thread (b = tid>>4, kc = tid&15): batch-loads h[b][kc-chunk] (64 floats) as
// 16 coalesced sc1 dwordx4, computes 12 row-partials from LDS W (broadcast),
// LDS-reduce over kc, 64 threads gate + sc1-store new h.
__global__ __launch_bounds__(256, 1) void gru_scan(const float* __restrict__ xp,
                                                   const float* __restrict__ Whh,
                                                   const float* __restrict__ bhh,
                                                   const float* __restrict__ h0src,
                                                   float* __restrict__ ys,
                                                   float* __restrict__ buf0,
                                                   float* __restrict__ buf1,
                                                   float* __restrict__ hid,
                                                   unsigned* __restrict__ flags,
                                                   unsigned* __restrict__ gen,
                                                   unsigned gen_base) {
    __shared__ float w_lds[12 * 1028];      // 12 rows, stride 1028 (16B-aligned)
    __shared__ float red[16 * 200];         // [kc][rr*16+b], stride 200 vs conflicts
    __shared__ float sum_lds[192];
    __shared__ float bhh_lds[12];

    int wg = blockIdx.x;
    int j0 = wg * 4;
    int tid = threadIdx.x;

    // stage the 12 W_hh rows for this WG into LDS (coalesced float4)
    for (int rr = 0; rr < 12; rr++) {
        int gate = rr >> 2, jloc = rr & 3;
        int grow = gate * FEAT + j0 + jloc;
        float4 v = ((const float4*)(Whh + (size_t)grow * FEAT))[tid];
        *(float4*)(w_lds + rr * 1028 + tid * 4) = v;
    }
    if (tid < 12) {
        int gate = tid >> 2, jloc = tid & 3;
        bhh_lds[tid] = bhh[gate * FEAT + j0 + jloc];
    }
    __syncthreads();

    int b  = tid >> 4;        // 0..15 batch
    int kc = tid & 15;        // 0..15 k-chunk (16B each, strided by 256B)
    int pb = tid >> 2, pjl = tid & 3, pj = j0 + pjl;   // gating mapping (tid<64)

    for (int t = 0; t < NT; t++) {
        const float* hc = (t == 0) ? h0src : ((t & 1) ? buf0 : buf1);
        float* hn = (t & 1) ? buf1 : buf0;

        // ---- prefetch xp gate values (plain) + h_old (sc1, issue-only) ----
        float xr = 0.f, xz = 0.f, xn = 0.f;
        float hold;
        if (tid < 64) {
            const float* xpr = xp + (size_t)(t * NB + pb) * G3;
            xr = xpr[pj];
            xz = xpr[FEAT + pj];
            xn = xpr[2 * FEAT + pj];
            asm volatile("global_load_dword %0, %1, off sc0 sc1"
                         : "=&v"(hold) : "v"(hc + pb * FEAT + pj) : "memory");
        }

        // ---- batched coherent load of this thread's h chunk (64 floats) ----
        f4 h4[16];
        {
            const float* hptr = hc + b * FEAT + kc * 4;
            asm volatile(
                "global_load_dwordx4 %0,  %16, off sc0 sc1\n\t"
                "global_load_dwordx4 %1,  %16, off offset:256 sc0 sc1\n\t"
                "global_load_dwordx4 %2,  %16, off offset:512 sc0 sc1\n\t"
                "global_load_dwordx4 %3,  %16, off offset:768 sc0 sc1\n\t"
                "global_load_dwordx4 %4,  %16, off offset:1024 sc0 sc1\n\t"
                "global_load_dwordx4 %5,  %16, off offset:1280 sc0 sc1\n\t"
                "global_load_dwordx4 %6,  %16, off offset:1536 sc0 sc1\n\t"
                "global_load_dwordx4 %7,  %16, off offset:1792 sc0 sc1\n\t"
                "global_load_dwordx4 %8,  %16, off offset:2048 sc0 sc1\n\t"
                "global_load_dwordx4 %9,  %16, off offset:2304 sc0 sc1\n\t"
                "global_load_dwordx4 %10, %16, off offset:2560 sc0 sc1\n\t"
                "global_load_dwordx4 %11, %16, off offset:2816 sc0 sc1\n\t"
                "global_load_dwordx4 %12, %16, off offset:3072 sc0 sc1\n\t"
                "global_load_dwordx4 %13, %16, off offset:3328 sc0 sc1\n\t"
                "global_load_dwordx4 %14, %16, off offset:3584 sc0 sc1\n\t"
                "global_load_dwordx4 %15, %16, off offset:3840 sc0 sc1\n\t"
                "s_waitcnt vmcnt(0)"
                : "=&v"(h4[0]), "=&v"(h4[1]), "=&v"(h4[2]), "=&v"(h4[3]),
                  "=&v"(h4[4]), "=&v"(h4[5]), "=&v"(h4[6]), "=&v"(h4[7]),
                  "=&v"(h4[8]), "=&v"(h4[9]), "=&v"(h4[10]), "=&v"(h4[11]),
                  "=&v"(h4[12]), "=&v"(h4[13]), "=&v"(h4[14]), "=&v"(h4[15])
                : "v"(hptr) : "memory");
            __builtin_amdgcn_sched_barrier(0);   // don't let uses hoist above wait
        }

        // ---- 12 row-partials over this thread's 64 k-elements ----
        float part[12];
#pragma unroll
        for (int rr = 0; rr < 12; rr++) part[rr] = 0.f;
#pragma unroll
        for (int q = 0; q < 16; q++) {
            int kof = q * 64 + kc * 4;           // matches load offset q*256B
#pragma unroll
            for (int rr = 0; rr < 12; rr++) {
                f4 w = *(const f4*)&w_lds[rr * 1028 + kof];
                part[rr] = fmaf(h4[q].x, w.x, part[rr]);
                part[rr] = fmaf(h4[q].y, w.y, part[rr]);
                part[rr] = fmaf(h4[q].z, w.z, part[rr]);
                part[rr] = fmaf(h4[q].w, w.w, part[rr]);
            }
        }
#pragma unroll
        for (int rr = 0; rr < 12; rr++)
            red[kc * 200 + rr * 16 + b] = part[rr];

        asm volatile("s_waitcnt vmcnt(0)" ::: "memory");   // hold complete
        __builtin_amdgcn_sched_barrier(0);
        __syncthreads();

        if (tid < 192) {
            float s = 0.f;
#pragma unroll
            for (int q = 0; q < 16; q++) s += red[q * 200 + tid];
            sum_lds[tid] = s;
        }
        __syncthreads();

        if (tid < 64) {
            float dr = sum_lds[pjl * 16 + pb] + bhh_lds[pjl];
            float dz = sum_lds[(4 + pjl) * 16 + pb] + bhh_lds[4 + pjl];
            float dn = sum_lds[(8 + pjl) * 16 + pb] + bhh_lds[8 + pjl];
            float r = 1.f / (1.f + expf(-(xr + dr)));
            float z = 1.f / (1.f + expf(-(xz + dz)));
            float n = tanhf(xn + r * dn);
            float hv = (1.f - z) * n + z * hold;
            store_f32_sc(hn + pb * FEAT + pj, hv);       // coherent h publish
            ys[(size_t)(t * NB + pb) * FEAT + pj] = hv;  // plain (next kernel)
            if (t == NT - 1) hid[pb * FEAT + pj] = hv;
        }
        grid_barrier4(flags, gen, gen_base + t + 1, wg, tid);
    }
}

// ---------------- launcher ----------------
extern "C" void kernel_launch(void* const* d_in, const int* in_sizes, int n_in,
                              void* d_out, int out_size, void* d_ws, size_t ws_size,
                              hipStream_t stream) {
    const int*   x     = (const int*)d_in[0];
    const float* h0    = (const float*)d_in[1];
    const float* emb   = (const float*)d_in[2];
    const float* W_ih0 = (const float*)d_in[3];
    const float* W_hh0 = (const float*)d_in[4];
    const float* b_ih0 = (const float*)d_in[5];
    const float* b_hh0 = (const float*)d_in[6];
    const float* W_ih1 = (const float*)d_in[7];
    const float* W_hh1 = (const float*)d_in[8];
    const float* b_ih1 = (const float*)d_in[9];
    const float* b_hh1 = (const float*)d_in[10];
    const float* dec_b = (const float*)d_in[11];

    float* out = (float*)d_out;
    float* hid_out = out + (size_t)NB * NT * VOCAB;

    float* ws  = (float*)d_ws;
    float* xp  = ws;                                    // [4096][3072]
    float* xs  = xp + (size_t)4096 * 3072;              // [4096][1024] (also ys1)
    float* ys0 = xs + (size_t)4096 * 1024;              // [4096][1024]
    float* ha  = ys0 + (size_t)4096 * 1024;             // [16][1024]
    float* hb  = ha + NB * FEAT;                        // [16][1024]
    unsigned* flags = (unsigned*)(hb + NB * FEAT);      // 256 * 32 uints (128B apart)
    unsigned* gen   = flags + NWG * FLAG_STRIDE;        // 1 uint
    float* ys1 = xs;                                    // reuse (xs dead after xp0)

    // 0. zero the barrier state (flags + gen)
    hipMemsetAsync((void*)flags, 0, (NWG * FLAG_STRIDE + 1) * sizeof(unsigned), stream);

    // 1. gather
    gather_kernel<<<dim3(NT * NB), dim3(256), 0, stream>>>(x, emb, xs);

    // 2. x_proj layer 0
    gemm_f32<<<dim3(G3 / 128, 4096 / 128), dim3(256), 0, stream>>>(
        xs, W_ih0, b_ih0, xp, 4096, G3, FEAT, 0);

    // 3. scan layer 0 (persistent, fence-free barrier; gens 1..256)
    gru_scan<<<dim3(NWG), dim3(256), 0, stream>>>(
        xp, W_hh0, b_hh0, h0, ys0, ha, hb, hid_out, flags, gen, 0u);

    // 4. x_proj layer 1 (reuses xp)
    gemm_f32<<<dim3(G3 / 128, 4096 / 128), dim3(256), 0, stream>>>(
        ys0, W_ih1, b_ih1, xp, 4096, G3, FEAT, 0);

    // 5. scan layer 1 (gens 257..512)
    gru_scan<<<dim3(NWG), dim3(256), 0, stream>>>(
        xp, W_hh1, b_hh1, h0 + NB * FEAT, ys1, ha, hb, hid_out + NB * FEAT,
        flags, gen, (unsigned)NT);

    // 6. tied decoder: logits[b*T+t][v] = ys1[t*B+b] . emb[v] + dec_b[v]
    gemm_f32<<<dim3(VOCAB / 128, 4096 / 128), dim3(256), 0, stream>>>(
        ys1, emb, dec_b, out, 4096, VOCAB, FEAT, 1);
}

// Round 6
// 3887.257 us; speedup vs baseline: 7.0830x; 1.7008x over previous
//
#include <hip/hip_runtime.h>
#include <math.h>

#define FEAT 1024
#define NB 16       // batch
#define NT 256      // seq len
#define VOCAB 32000
#define G3 3072     // 3*FEAT
#define NWG 256     // scan workgroups
#define FLAG_STRIDE 32   // 128B between flags -> no cacheline sharing

#define BK 32       // K-step of the MFMA GEMM
#define LDH 40      // f16 row stride in LDS (80B: 16-row b128 reads = 2-way = free)

typedef float f4 __attribute__((ext_vector_type(4)));
typedef float f32x4 __attribute__((ext_vector_type(4)));
typedef _Float16 half4v __attribute__((ext_vector_type(4)));
typedef _Float16 half8v __attribute__((ext_vector_type(8)));

// ---------------- embedding gather: xs[t*NB+b][:] = emb[x[b][t]] ----------------
__global__ __launch_bounds__(256) void gather_kernel(const int* __restrict__ x,
                                                     const float* __restrict__ emb,
                                                     float* __restrict__ xs) {
    int row = blockIdx.x;          // row = t*NB + b  (time-major)
    int t = row >> 4;
    int b = row & 15;
    int tok = x[b * NT + t];
    const float4* src = (const float4*)(emb + (size_t)tok * FEAT);
    float4* dst = (float4*)(xs + (size_t)row * FEAT);
    dst[threadIdx.x] = src[threadIdx.x];   // 256 threads * 4 floats = 1024
}

// ---------------- split-f16 MFMA GEMM ----------------
// C[M][N] = A[M][K]*B[N][K]^T + bias[N], fp32 in/out, internally f16 hi/lo split:
//   C = Ah*Bh + Ah*Bl + Al*Bh  (lo*lo dropped, ~2^-22 relative)
// 128x128 tile, 4 waves 2x2, BK=32, on-the-fly fp32->f16 conversion into LDS.
// perm!=0: C row m is written to row ((m&15)<<8)|(m>>4)  (t*B+b -> b*T+t)
// Grid 1D: groups of GM m-tiles sweep N together (B-panel L2/LLC reuse).
__global__ __launch_bounds__(256, 2) void gemm_split16(
        const float* __restrict__ A, const float* __restrict__ Bm,
        const float* __restrict__ bias, float* __restrict__ C,
        int M, int N, int K, int GM, int perm) {
    __shared__ _Float16 AhS[128 * LDH];
    __shared__ _Float16 AlS[128 * LDH];
    __shared__ _Float16 BhS[128 * LDH];
    __shared__ _Float16 BlS[128 * LDH];

    int nNt = N >> 7;
    int perGroup = GM * nNt;
    int g = blockIdx.x / perGroup;
    int rix = blockIdx.x % perGroup;
    int n_t = rix / GM;
    int m_t = g * GM + (rix % GM);

    int tid = threadIdx.x;
    int srow = tid >> 1;          // 0..127 staging row
    int shf = tid & 1;            // k-half: 0 -> k 0..15, 1 -> k 16..31

    const float* aptr = A + (size_t)(m_t * 128 + srow) * K + shf * 16;
    const float* bptr = Bm + (size_t)(n_t * 128 + srow) * K + shf * 16;

    int wid = tid >> 6;
    int wr = wid >> 1, wc = wid & 1;      // wave 2x2
    int lane = tid & 63;
    int fr = lane & 15;                   // frag row (A) / col (B,D)
    int ke = lane >> 4;                   // k-block 0..3 (8 halves each)

    f32x4 acc[4][4];
#pragma unroll
    for (int i = 0; i < 4; i++)
#pragma unroll
        for (int j = 0; j < 4; j++) acc[i][j] = (f32x4){0.f, 0.f, 0.f, 0.f};

    float4 a4[4], b4[4];
#pragma unroll
    for (int q = 0; q < 4; q++) {
        a4[q] = *(const float4*)(aptr + q * 4);
        b4[q] = *(const float4*)(bptr + q * 4);
    }

    for (int k0 = 0; k0 < K; k0 += BK) {
        __syncthreads();              // previous tile fully consumed
        // convert + stage (hi = f16(x), lo = f16(x - hi))
#pragma unroll
        for (int q = 0; q < 4; q++) {
            half4v hh, hl;
            hh.x = (_Float16)a4[q].x; hl.x = (_Float16)(a4[q].x - (float)hh.x);
            hh.y = (_Float16)a4[q].y; hl.y = (_Float16)(a4[q].y - (float)hh.y);
            hh.z = (_Float16)a4[q].z; hl.z = (_Float16)(a4[q].z - (float)hh.z);
            hh.w = (_Float16)a4[q].w; hl.w = (_Float16)(a4[q].w - (float)hh.w);
            int o = srow * LDH + shf * 16 + q * 4;
            *(half4v*)&AhS[o] = hh;
            *(half4v*)&AlS[o] = hl;
            half4v gh, gl;
            gh.x = (_Float16)b4[q].x; gl.x = (_Float16)(b4[q].x - (float)gh.x);
            gh.y = (_Float16)b4[q].y; gl.y = (_Float16)(b4[q].y - (float)gh.y);
            gh.z = (_Float16)b4[q].z; gl.z = (_Float16)(b4[q].z - (float)gh.z);
            gh.w = (_Float16)b4[q].w; gl.w = (_Float16)(b4[q].w - (float)gh.w);
            *(half4v*)&BhS[o] = gh;
            *(half4v*)&BlS[o] = gl;
        }
        __syncthreads();

        if (k0 + BK < K) {            // prefetch next k-tile (overlaps MFMA)
#pragma unroll
            for (int q = 0; q < 4; q++) {
                a4[q] = *(const float4*)(aptr + k0 + BK + q * 4);
                b4[q] = *(const float4*)(bptr + k0 + BK + q * 4);
            }
        }

        // fragment loads (b128, 16B-aligned: LDH*2=80, ke*16 both /16... 80*r+16*ke)
        half8v ah[4], al[4], bh[4], bl[4];
#pragma unroll
        for (int i = 0; i < 4; i++) {
            int ao = (wr * 64 + i * 16 + fr) * LDH + ke * 8;
            ah[i] = *(const half8v*)&AhS[ao];
            al[i] = *(const half8v*)&AlS[ao];
            int bo = (wc * 64 + i * 16 + fr) * LDH + ke * 8;
            bh[i] = *(const half8v*)&BhS[bo];
            bl[i] = *(const half8v*)&BlS[bo];
        }
#pragma unroll
        for (int i = 0; i < 4; i++)
#pragma unroll
            for (int j = 0; j < 4; j++) {
                acc[i][j] = __builtin_amdgcn_mfma_f32_16x16x32_f16(ah[i], bh[j], acc[i][j], 0, 0, 0);
                acc[i][j] = __builtin_amdgcn_mfma_f32_16x16x32_f16(ah[i], bl[j], acc[i][j], 0, 0, 0);
                acc[i][j] = __builtin_amdgcn_mfma_f32_16x16x32_f16(al[i], bh[j], acc[i][j], 0, 0, 0);
            }
    }

    // epilogue: D col = lane&15, row = 4*(lane>>4)+v (m89-verified mapping)
#pragma unroll
    for (int j = 0; j < 4; j++) {
        int col = n_t * 128 + wc * 64 + j * 16 + fr;
        float bv = bias[col];
#pragma unroll
        for (int i = 0; i < 4; i++) {
#pragma unroll
            for (int v = 0; v < 4; v++) {
                int mrow = m_t * 128 + wr * 64 + i * 16 + 4 * ke + v;
                int orow = perm ? (((mrow & 15) << 8) | (mrow >> 4)) : mrow;
                C[(size_t)orow * N + col] = acc[i][j][v] + bv;
            }
        }
    }
}

// ---------------- agent-coherent scalar ops (bypass non-coherent L2, hit LLC) ----
__device__ __forceinline__ void store_f32_sc(float* p, float v) {
    asm volatile("global_store_dword %0, %1, off sc0 sc1" :: "v"(p), "v"(v) : "memory");
}

// ---------------- fence-free grid barrier ----------------
// All cross-block data (h, flags, gen) moves via sc0/sc1 ops -> always at LLC.
// No buffer_wbl2 / buffer_inv anywhere: L2 stays warm for xp/W across steps.
__device__ __forceinline__ void grid_barrier4(unsigned* __restrict__ flags,
                                              unsigned* __restrict__ gen,
                                              unsigned expected, int bid, int tid) {
    __syncthreads();                    // drains all waves' sc1 h-stores
    if (tid == 0) {
        __hip_atomic_store(&flags[bid * FLAG_STRIDE], expected,
                           __ATOMIC_RELAXED, __HIP_MEMORY_SCOPE_AGENT);
    }
    if (bid == 0) {
        unsigned v; int spins = 0;
        do {
            v = __hip_atomic_load(&flags[tid * FLAG_STRIDE],
                                  __ATOMIC_RELAXED, __HIP_MEMORY_SCOPE_AGENT);
        } while (v < expected && ++spins < (1 << 18));
        __syncthreads();                // all 256 flags seen
        if (tid == 0) {
            __hip_atomic_store(gen, expected,
                               __ATOMIC_RELAXED, __HIP_MEMORY_SCOPE_AGENT);
        }
    } else {
        if (tid == 0) {
            unsigned v; int spins = 0;
            do {
                v = __hip_atomic_load(gen, __ATOMIC_RELAXED,
                                      __HIP_MEMORY_SCOPE_AGENT);
                if (v >= expected) break;
                __builtin_amdgcn_s_sleep(1);
            } while (++spins < (1 << 18));
        }
    }
    __syncthreads();
}

// ---------------- persistent GRU scan (one layer) ----------------
__global__ __launch_bounds__(256, 1) void gru_scan(const float* __restrict__ xp,
                                                   const float* __restrict__ Whh,
                                                   const float* __restrict__ bhh,
                                                   const float* __restrict__ h0src,
                                                   float* __restrict__ ys,
                                                   float* __restrict__ buf0,
                                                   float* __restrict__ buf1,
                                                   float* __restrict__ hid,
                                                   unsigned* __restrict__ flags,
                                                   unsigned* __restrict__ gen,
                                                   unsigned gen_base) {
    __shared__ float w_lds[12 * 1028];      // 12 rows, stride 1028 (16B-aligned)
    __shared__ float red[16 * 200];         // [kc][rr*16+b]
    __shared__ float sum_lds[192];
    __shared__ float bhh_lds[12];

    int wg = blockIdx.x;
    int j0 = wg * 4;
    int tid = threadIdx.x;

    for (int rr = 0; rr < 12; rr++) {
        int gate = rr >> 2, jloc = rr & 3;
        int grow = gate * FEAT + j0 + jloc;
        float4 v = ((const float4*)(Whh + (size_t)grow * FEAT))[tid];
        *(float4*)(w_lds + rr * 1028 + tid * 4) = v;
    }
    if (tid < 12) {
        int gate = tid >> 2, jloc = tid & 3;
        bhh_lds[tid] = bhh[gate * FEAT + j0 + jloc];
    }
    __syncthreads();

    int b  = tid >> 4;        // 0..15 batch
    int kc = tid & 15;        // 0..15 k-chunk
    int pb = tid >> 2, pjl = tid & 3, pj = j0 + pjl;   // gating mapping (tid<64)

    for (int t = 0; t < NT; t++) {
        const float* hc = (t == 0) ? h0src : ((t & 1) ? buf0 : buf1);
        float* hn = (t & 1) ? buf1 : buf0;

        float xr = 0.f, xz = 0.f, xn = 0.f;
        float hold;
        if (tid < 64) {
            const float* xpr = xp + (size_t)(t * NB + pb) * G3;
            xr = xpr[pj];
            xz = xpr[FEAT + pj];
            xn = xpr[2 * FEAT + pj];
            asm volatile("global_load_dword %0, %1, off sc0 sc1"
                         : "=&v"(hold) : "v"(hc + pb * FEAT + pj) : "memory");
        }

        f4 h4[16];
        {
            const float* hptr = hc + b * FEAT + kc * 4;
            asm volatile(
                "global_load_dwordx4 %0,  %16, off sc0 sc1\n\t"
                "global_load_dwordx4 %1,  %16, off offset:256 sc0 sc1\n\t"
                "global_load_dwordx4 %2,  %16, off offset:512 sc0 sc1\n\t"
                "global_load_dwordx4 %3,  %16, off offset:768 sc0 sc1\n\t"
                "global_load_dwordx4 %4,  %16, off offset:1024 sc0 sc1\n\t"
                "global_load_dwordx4 %5,  %16, off offset:1280 sc0 sc1\n\t"
                "global_load_dwordx4 %6,  %16, off offset:1536 sc0 sc1\n\t"
                "global_load_dwordx4 %7,  %16, off offset:1792 sc0 sc1\n\t"
                "global_load_dwordx4 %8,  %16, off offset:2048 sc0 sc1\n\t"
                "global_load_dwordx4 %9,  %16, off offset:2304 sc0 sc1\n\t"
                "global_load_dwordx4 %10, %16, off offset:2560 sc0 sc1\n\t"
                "global_load_dwordx4 %11, %16, off offset:2816 sc0 sc1\n\t"
                "global_load_dwordx4 %12, %16, off offset:3072 sc0 sc1\n\t"
                "global_load_dwordx4 %13, %16, off offset:3328 sc0 sc1\n\t"
                "global_load_dwordx4 %14, %16, off offset:3584 sc0 sc1\n\t"
                "global_load_dwordx4 %15, %16, off offset:3840 sc0 sc1\n\t"
                "s_waitcnt vmcnt(0)"
                : "=&v"(h4[0]), "=&v"(h4[1]), "=&v"(h4[2]), "=&v"(h4[3]),
                  "=&v"(h4[4]), "=&v"(h4[5]), "=&v"(h4[6]), "=&v"(h4[7]),
                  "=&v"(h4[8]), "=&v"(h4[9]), "=&v"(h4[10]), "=&v"(h4[11]),
                  "=&v"(h4[12]), "=&v"(h4[13]), "=&v"(h4[14]), "=&v"(h4[15])
                : "v"(hptr) : "memory");
            __builtin_amdgcn_sched_barrier(0);
        }

        float part[12];
#pragma unroll
        for (int rr = 0; rr < 12; rr++) part[rr] = 0.f;
#pragma unroll
        for (int q = 0; q < 16; q++) {
            int kof = q * 64 + kc * 4;
#pragma unroll
            for (int rr = 0; rr < 12; rr++) {
                f4 w = *(const f4*)&w_lds[rr * 1028 + kof];
                part[rr] = fmaf(h4[q].x, w.x, part[rr]);
                part[rr] = fmaf(h4[q].y, w.y, part[rr]);
                part[rr] = fmaf(h4[q].z, w.z, part[rr]);
                part[rr] = fmaf(h4[q].w, w.w, part[rr]);
            }
        }
#pragma unroll
        for (int rr = 0; rr < 12; rr++)
            red[kc * 200 + rr * 16 + b] = part[rr];

        asm volatile("s_waitcnt vmcnt(0)" ::: "memory");   // hold complete
        __builtin_amdgcn_sched_barrier(0);
        __syncthreads();

        if (tid < 192) {
            float s = 0.f;
#pragma unroll
            for (int q = 0; q < 16; q++) s += red[q * 200 + tid];
            sum_lds[tid] = s;
        }
        __syncthreads();

        if (tid < 64) {
            float dr = sum_lds[pjl * 16 + pb] + bhh_lds[pjl];
            float dz = sum_lds[(4 + pjl) * 16 + pb] + bhh_lds[4 + pjl];
            float dn = sum_lds[(8 + pjl) * 16 + pb] + bhh_lds[8 + pjl];
            float r = 1.f / (1.f + expf(-(xr + dr)));
            float z = 1.f / (1.f + expf(-(xz + dz)));
            float n = tanhf(xn + r * dn);
            float hv = (1.f - z) * n + z * hold;
            store_f32_sc(hn + pb * FEAT + pj, hv);       // coherent h publish
            ys[(size_t)(t * NB + pb) * FEAT + pj] = hv;  // plain (next kernel)
            if (t == NT - 1) hid[pb * FEAT + pj] = hv;
        }
        grid_barrier4(flags, gen, gen_base + t + 1, wg, tid);
    }
}

// ---------------- launcher ----------------
extern "C" void kernel_launch(void* const* d_in, const int* in_sizes, int n_in,
                              void* d_out, int out_size, void* d_ws, size_t ws_size,
                              hipStream_t stream) {
    const int*   x     = (const int*)d_in[0];
    const float* h0    = (const float*)d_in[1];
    const float* emb   = (const float*)d_in[2];
    const float* W_ih0 = (const float*)d_in[3];
    const float* W_hh0 = (const float*)d_in[4];
    const float* b_ih0 = (const float*)d_in[5];
    const float* b_hh0 = (const float*)d_in[6];
    const float* W_ih1 = (const float*)d_in[7];
    const float* W_hh1 = (const float*)d_in[8];
    const float* b_ih1 = (const float*)d_in[9];
    const float* b_hh1 = (const float*)d_in[10];
    const float* dec_b = (const float*)d_in[11];

    float* out = (float*)d_out;
    float* hid_out = out + (size_t)NB * NT * VOCAB;

    float* ws  = (float*)d_ws;
    float* xp  = ws;                                    // [4096][3072]
    float* xs  = xp + (size_t)4096 * 3072;              // [4096][1024] (also ys1)
    float* ys0 = xs + (size_t)4096 * 1024;              // [4096][1024]
    float* ha  = ys0 + (size_t)4096 * 1024;             // [16][1024]
    float* hb  = ha + NB * FEAT;                        // [16][1024]
    unsigned* flags = (unsigned*)(hb + NB * FEAT);      // 256 * 32 uints
    unsigned* gen   = flags + NWG * FLAG_STRIDE;        // 1 uint
    float* ys1 = xs;                                    // reuse (xs dead after xp0)

    // 0. zero the barrier state (flags + gen)
    hipMemsetAsync((void*)flags, 0, (NWG * FLAG_STRIDE + 1) * sizeof(unsigned), stream);

    // 1. gather
    gather_kernel<<<dim3(NT * NB), dim3(256), 0, stream>>>(x, emb, xs);

    // 2. x_proj layer 0 (split-f16 MFMA): xp = xs * W_ih0^T + b_ih0
    gemm_split16<<<dim3((4096 / 128) * (G3 / 128)), dim3(256), 0, stream>>>(
        xs, W_ih0, b_ih0, xp, 4096, G3, FEAT, 8, 0);

    // 3. scan layer 0 (persistent, fence-free barrier; gens 1..256)
    gru_scan<<<dim3(NWG), dim3(256), 0, stream>>>(
        xp, W_hh0, b_hh0, h0, ys0, ha, hb, hid_out, flags, gen, 0u);

    // 4. x_proj layer 1
    gemm_split16<<<dim3((4096 / 128) * (G3 / 128)), dim3(256), 0, stream>>>(
        ys0, W_ih1, b_ih1, xp, 4096, G3, FEAT, 8, 0);

    // 5. scan layer 1 (gens 257..512)
    gru_scan<<<dim3(NWG), dim3(256), 0, stream>>>(
        xp, W_hh1, b_hh1, h0 + NB * FEAT, ys1, ha, hb, hid_out + NB * FEAT,
        flags, gen, (unsigned)NT);

    // 6. tied decoder (split-f16 MFMA, perm on C-write):
    //    logits[b*T+t][v] = ys1[t*B+b] . emb[v] + dec_b[v]
    gemm_split16<<<dim3((4096 / 128) * (VOCAB / 128)), dim3(256), 0, stream>>>(
        ys1, emb, dec_b, out, 4096, VOCAB, FEAT, 8, 1);
}